// Round 3
// baseline (294.328 us; speedup 1.0000x reference)
//
#include <hip/hip_runtime.h>
#include <math.h>

static constexpr float kL1   = 0.5f;
static constexpr float kL2   = 1.5f;
static constexpr float kBeta = 50000000.0f;
static constexpr float kEps  = 1e-08f;

typedef float f32x4 __attribute__((ext_vector_type(4)));

__device__ __forceinline__ float waveSum(float v) {
#pragma unroll
    for (int off = 32; off > 0; off >>= 1) v += __shfl_xor(v, off, 64);
    return v;
}

__device__ __forceinline__ float tubeTail(float dot, float pp, float gg) {
    float p_norm = sqrtf(pp);
    float g_norm = sqrtf(gg);
    float denom  = p_norm * g_norm;
    float cosine = (denom == 0.0f) ? 0.0f : dot / denom;
    float s_s    = 1.0f - cosine * cosine;
    float sine   = (s_s < 0.0f) ? 0.0f : sqrtf((s_s <= 0.0f) ? kEps : s_s);
    float gd     = (g_norm == 0.0f) ? (g_norm + kEps) : g_norm;
    float pc     = p_norm * cosine;
    float r_all  = pc / gd;
    float base   = p_norm * sine + fabsf(g_norm - pc);
    float ds     = (r_all >= 1.0f) ? (kL1 * base)
                 : ((r_all >= 0.0f) ? base
                                    : kL2 * fabsf(pc - g_norm - p_norm * sine));
    // -log(tanh(t)) = log(1+e^{-2t}) - log(1-e^{-2t})
    float t  = 1.0f / ds;
    float em = __expf(-2.0f * t);
    return __logf(1.0f + em) - __logf(fmaxf(1.0f - em, 1e-30f));
}

#define ACC3(dot, pp, gg, A, L)                           \
    dot += A.x*L.x + A.y*L.y + A.z*L.z + A.w*L.w;         \
    pp  += A.x*A.x + A.y*A.y + A.z*A.z + A.w*A.w;         \
    gg  += L.x*L.x + L.y*L.y + L.z*L.z + L.w*L.w;

//   blocks [0, tubeBlocks)            : tube — 4 rows (2 pairs, 16 KB) per wave-iter
//   blocks [tubeBlocks, +klBlocks)    : KL   — 2 float4-pairs per thread (exact fit)
//   blocks [tubeBlocks+klBlocks, end) : CE   — 1 row per wave
__global__ __launch_bounds__(256, 2) void fused_loss_partials(
    const float* __restrict__ fusion_out, const float* __restrict__ comple_out,
    const float* __restrict__ labels,     const float* __restrict__ labels_enc,
    const float* __restrict__ xA,  const float* __restrict__ xAr,
    const float* __restrict__ xB,  const float* __restrict__ xBr,
    const float* __restrict__ xC,  const float* __restrict__ xCr,
    const float* __restrict__ mu,  const float* __restrict__ logvar,
    float* __restrict__ partials,
    int C, int Z, int tubeBlocks, int klBlocks)
{
    const int lane = threadIdx.x & 63;
    const int wave = threadIdx.x >> 6;
    const int bid  = blockIdx.x;
    constexpr int B = 16384;
    constexpr int D = 512;

    float my = 0.0f;

    if (bid < tubeBlocks) {
        // ---- TUBE: quad q = rows (4q .. 4q+3) of one tensor; half-wave h owns
        //      row (base+h) of each pair. 16 float4 loads forced simultaneously
        //      live -> 16 KB in flight per wave before the first wait. ----
        const int h   = lane >> 5;
        const int sub = lane & 31;
        const int nQuads = B;                       // 4*B rows / 4
        const int gw = bid * 4 + wave;
        const int tw = tubeBlocks * 4;
        float acc = 0.0f;
        for (int q = gw; q < nQuads; q += tw) {
            const int p = q >> 12;                  // 4096 quads per tensor
            const int r = (q << 2) & (B - 1);       // base row within tensor
            const float* ab = (p == 0) ? xAr : (p == 1) ? xBr : (p == 2) ? xCr : comple_out;
            const float* lb = (p == 0) ? xA  : (p == 1) ? xB  : (p == 2) ? xC  : labels_enc;
            const f32x4* a0 = (const f32x4*)(ab + (size_t)r * D) + (h * 128 + sub);
            const f32x4* l0 = (const f32x4*)(lb + (size_t)r * D) + (h * 128 + sub);
            const f32x4* a1 = a0 + 256;             // rows r+2, r+3
            const f32x4* l1 = l0 + 256;

            f32x4 A0 = a0[0], A1 = a0[32], A2 = a0[64], A3 = a0[96];
            f32x4 L0 = l0[0], L1 = l0[32], L2 = l0[64], L3 = l0[96];
            f32x4 A4 = a1[0], A5 = a1[32], A6 = a1[64], A7 = a1[96];
            f32x4 L4 = l1[0], L5 = l1[32], L6 = l1[64], L7 = l1[96];
            // Force all 16 payloads to be live at once: compiler must issue all
            // 16 loads before the first consuming wait (no serialization).
            asm volatile("" ::
                "v"(A0), "v"(A1), "v"(A2), "v"(A3),
                "v"(L0), "v"(L1), "v"(L2), "v"(L3),
                "v"(A4), "v"(A5), "v"(A6), "v"(A7),
                "v"(L4), "v"(L5), "v"(L6), "v"(L7));

            float dot0 = 0.0f, pp0 = 0.0f, gg0 = 0.0f;
            float dot1 = 0.0f, pp1 = 0.0f, gg1 = 0.0f;
            ACC3(dot0, pp0, gg0, A0, L0); ACC3(dot0, pp0, gg0, A1, L1);
            ACC3(dot0, pp0, gg0, A2, L2); ACC3(dot0, pp0, gg0, A3, L3);
            ACC3(dot1, pp1, gg1, A4, L4); ACC3(dot1, pp1, gg1, A5, L5);
            ACC3(dot1, pp1, gg1, A6, L6); ACC3(dot1, pp1, gg1, A7, L7);

            // two interleaved 5-step butterflies (6 independent chains -> DS ILP)
#pragma unroll
            for (int off = 16; off > 0; off >>= 1) {
                dot0 += __shfl_xor(dot0, off, 64);
                pp0  += __shfl_xor(pp0,  off, 64);
                gg0  += __shfl_xor(gg0,  off, 64);
                dot1 += __shfl_xor(dot1, off, 64);
                pp1  += __shfl_xor(pp1,  off, 64);
                gg1  += __shfl_xor(gg1,  off, 64);
            }
            // two independent tails, both halves active (replicated x32 per half)
            acc += tubeTail(dot0, pp0, gg0);
            acc += tubeTail(dot1, pp1, gg1);
        }
        my = acc * (1.0f / (32.0f * (float)B));
    } else if (bid < tubeBlocks + klBlocks) {
        // ---- KL: two coalesced float4 sweeps, one pair per thread each ----
        const int base = (bid - tubeBlocks) * 512 + threadIdx.x;
        const int i0 = base, i1 = base + 256;
        const f32x4* mu4 = (const f32x4*)mu;
        const f32x4* lv4 = (const f32x4*)logvar;
        f32x4 m0 = mu4[i0], l0 = lv4[i0], m1 = mu4[i1], l1 = lv4[i1];
        asm volatile("" :: "v"(m0), "v"(l0), "v"(m1), "v"(l1));
        float acc = (1.0f + l0.x - m0.x * m0.x - __expf(l0.x))
                  + (1.0f + l0.y - m0.y * m0.y - __expf(l0.y))
                  + (1.0f + l0.z - m0.z * m0.z - __expf(l0.z))
                  + (1.0f + l0.w - m0.w * m0.w - __expf(l0.w))
                  + (1.0f + l1.x - m1.x * m1.x - __expf(l1.x))
                  + (1.0f + l1.y - m1.y * m1.y - __expf(l1.y))
                  + (1.0f + l1.z - m1.z * m1.z - __expf(l1.z))
                  + (1.0f + l1.w - m1.w * m1.w - __expf(l1.w));
        my = acc * (-0.5f * kBeta / ((float)B * (float)Z));
    } else {
        // ---- CE: one row per wave over C=100 ----
        const int r = (bid - tubeBlocks - klBlocks) * 4 + wave;   // < B
        const float* lrow = labels     + (size_t)r * C;
        const float* frow = fusion_out + (size_t)r * C;
        const bool has0 = (lane < C);
        const bool has1 = (lane + 64 < C);
        float v0 = has0 ? lrow[lane]      : -INFINITY;
        float v1 = has1 ? lrow[lane + 64] : -INFINITY;
        float f0 = has0 ? frow[lane]      : -INFINITY;
        float f1 = has1 ? frow[lane + 64] : -INFINITY;
        float bv; int bi;
        if (v1 > v0) { bv = v1; bi = lane + 64; } else { bv = v0; bi = lane; }
#pragma unroll
        for (int off = 32; off > 0; off >>= 1) {
            float ov = __shfl_xor(bv, off, 64);
            int   oi = __shfl_xor(bi, off, 64);
            if (ov > bv || (ov == bv && oi < bi)) { bv = ov; bi = oi; }
        }
        float m = fmaxf(f0, f1);
#pragma unroll
        for (int off = 32; off > 0; off >>= 1) m = fmaxf(m, __shfl_xor(m, off, 64));
        float e = 0.0f;
        if (has0) e += __expf(f0 - m);
        if (has1) e += __expf(f1 - m);
        e = waveSum(e);
        float tgt = (bi < 64) ? __shfl(f0, bi, 64) : __shfl(f1, bi - 64, 64);
        if (lane == 0) my = -(tgt - m - __logf(e)) / (float)B;
    }

    // ---- block reduce -> per-block partial (no atomics) ----
    float s = waveSum(my);
    __shared__ float sw[4];
    if (lane == 0) sw[wave] = s;
    __syncthreads();
    if (threadIdx.x == 0)
        partials[bid] = sw[0] + sw[1] + sw[2] + sw[3];
}

__global__ __launch_bounds__(256) void reduce_partials(
    const float* __restrict__ partials, float* __restrict__ out, int n)
{
    float s = 0.0f;
    for (int i = threadIdx.x; i < n; i += 256) s += partials[i];
    s = waveSum(s);
    __shared__ float sw[4];
    const int lane = threadIdx.x & 63;
    const int wave = threadIdx.x >> 6;
    if (lane == 0) sw[wave] = s;
    __syncthreads();
    if (threadIdx.x == 0) out[0] = sw[0] + sw[1] + sw[2] + sw[3];
}

extern "C" void kernel_launch(void* const* d_in, const int* in_sizes, int n_in,
                              void* d_out, int out_size, void* d_ws, size_t ws_size,
                              hipStream_t stream) {
    const float* fusion_out = (const float*)d_in[0];
    const float* comple_out = (const float*)d_in[1];
    const float* labels     = (const float*)d_in[2];
    const float* labels_enc = (const float*)d_in[3];
    const float* xA  = (const float*)d_in[4];
    const float* xAr = (const float*)d_in[5];
    const float* xB  = (const float*)d_in[6];
    const float* xBr = (const float*)d_in[7];
    const float* xC  = (const float*)d_in[8];
    const float* xCr = (const float*)d_in[9];
    const float* mu  = (const float*)d_in[10];
    const float* lv  = (const float*)d_in[11];
    float* out = (float*)d_out;
    float* ws  = (float*)d_ws;

    const int B = 16384;
    const int C = in_sizes[0] / B;    // 100
    const int Z = in_sizes[10] / B;   // 128

    const int tubeBlocks = 2048;                      // 8192 waves, 2 quads each
    const int klBlocks   = (B * Z / 4) / 512;         // 1024: 2 float4-pairs/thread
    const int ceBlocks   = B / 4;                     // 4096: 1 row/wave
    const int totalBlocks = tubeBlocks + klBlocks + ceBlocks;   // 7168

    fused_loss_partials<<<totalBlocks, 256, 0, stream>>>(
        fusion_out, comple_out, labels, labels_enc,
        xA, xAr, xB, xBr, xC, xCr, mu, lv,
        ws, C, Z, tubeBlocks, klBlocks);
    reduce_partials<<<1, 256, 0, stream>>>(ws, out, totalBlocks);
}

// Round 4
// 291.922 us; speedup vs baseline: 1.0082x; 1.0082x over previous
//
#include <hip/hip_runtime.h>
#include <math.h>

static constexpr float kL1   = 0.5f;
static constexpr float kL2   = 1.5f;
static constexpr float kBeta = 50000000.0f;
static constexpr float kEps  = 1e-08f;

typedef float f32x4 __attribute__((ext_vector_type(4)));
typedef unsigned long long u64;

__device__ __forceinline__ float waveSum(float v) {
#pragma unroll
    for (int off = 32; off > 0; off >>= 1) v += __shfl_xor(v, off, 64);
    return v;
}

__device__ __forceinline__ float tubeTail(float dot, float pp, float gg) {
    float p_norm = sqrtf(pp);
    float g_norm = sqrtf(gg);
    float denom  = p_norm * g_norm;
    float cosine = (denom == 0.0f) ? 0.0f : dot / denom;
    float s_s    = 1.0f - cosine * cosine;
    float sine   = (s_s < 0.0f) ? 0.0f : sqrtf((s_s <= 0.0f) ? kEps : s_s);
    float gd     = (g_norm == 0.0f) ? (g_norm + kEps) : g_norm;
    float pc     = p_norm * cosine;
    float r_all  = pc / gd;
    float base   = p_norm * sine + fabsf(g_norm - pc);
    float ds     = (r_all >= 1.0f) ? (kL1 * base)
                 : ((r_all >= 0.0f) ? base
                                    : kL2 * fabsf(pc - g_norm - p_norm * sine));
    // -log(tanh(t)) = log(1+e^{-2t}) - log(1-e^{-2t})
    float t  = 1.0f / ds;
    float em = __expf(-2.0f * t);
    return __logf(1.0f + em) - __logf(fmaxf(1.0f - em, 1e-30f));
}

#define ACC3(dot, pp, gg, A, L)                           \
    dot += A.x*L.x + A.y*L.y + A.z*L.z + A.w*L.w;         \
    pp  += A.x*A.x + A.y*A.y + A.z*A.z + A.w*A.w;         \
    gg  += L.x*L.x + L.y*L.y + L.z*L.z + L.w*L.w;

// Issue 8 dwordx4 loads (one row pair: att-row + label-row, 4 KB each tensor
// half... 8 x 512B wave-loads = 8 KB/wave) WITHOUT any wait. Compiler does not
// track these -> cannot sink them below the compute, cannot insert vmcnt(0).
#define TLOAD(d0,d1,d2,d3,e0,e1,e2,e3, av, lv)                       \
    asm volatile(                                                    \
        "global_load_dwordx4 %0, %8, off\n\t"                        \
        "global_load_dwordx4 %1, %8, off offset:512\n\t"             \
        "global_load_dwordx4 %2, %8, off offset:1024\n\t"            \
        "global_load_dwordx4 %3, %8, off offset:1536\n\t"            \
        "global_load_dwordx4 %4, %9, off\n\t"                        \
        "global_load_dwordx4 %5, %9, off offset:512\n\t"             \
        "global_load_dwordx4 %6, %9, off offset:1024\n\t"            \
        "global_load_dwordx4 %7, %9, off offset:1536\n\t"            \
        : "=&v"(d0), "=&v"(d1), "=&v"(d2), "=&v"(d3),                \
          "=&v"(e0), "=&v"(e1), "=&v"(e2), "=&v"(e3)                 \
        : "v"(av), "v"(lv))

// Counted wait: older batch done, newer batch (8 loads) stays in flight.
// sched_barrier(0) right after: rule #18 — stop hipcc hoisting register-only
// compute above the inline-asm waitcnt.
#define VMWAIT8() do { asm volatile("s_waitcnt vmcnt(8)");                    \
                       __builtin_amdgcn_sched_barrier(0); } while (0)
#define VMWAIT0() do { asm volatile("s_waitcnt vmcnt(0)");                    \
                       __builtin_amdgcn_sched_barrier(0); } while (0)

__device__ __forceinline__ void tubeCompute(
    f32x4 a0, f32x4 a1, f32x4 a2, f32x4 a3,
    f32x4 l0, f32x4 l1, f32x4 l2, f32x4 l3, float& acc)
{
    float dot = 0.0f, pp = 0.0f, gg = 0.0f;
    ACC3(dot, pp, gg, a0, l0); ACC3(dot, pp, gg, a1, l1);
    ACC3(dot, pp, gg, a2, l2); ACC3(dot, pp, gg, a3, l3);
    // 5-step butterfly within each 32-lane half (both halves = both rows)
#pragma unroll
    for (int off = 16; off > 0; off >>= 1) {
        dot += __shfl_xor(dot, off, 64);
        pp  += __shfl_xor(pp,  off, 64);
        gg  += __shfl_xor(gg,  off, 64);
    }
    acc += tubeTail(dot, pp, gg);
}

//   blocks [0, tubeBlocks)            : tube — 8 consecutive row-pairs per wave,
//                                       2-deep inline-asm load pipeline
//   blocks [tubeBlocks, +klBlocks)    : KL   — 2 float4-pairs per thread (exact)
//   blocks [tubeBlocks+klBlocks, end) : CE   — 1 row per wave
__global__ __launch_bounds__(256) void fused_loss_partials(
    const float* __restrict__ fusion_out, const float* __restrict__ comple_out,
    const float* __restrict__ labels,     const float* __restrict__ labels_enc,
    const float* __restrict__ xA,  const float* __restrict__ xAr,
    const float* __restrict__ xB,  const float* __restrict__ xBr,
    const float* __restrict__ xC,  const float* __restrict__ xCr,
    const float* __restrict__ mu,  const float* __restrict__ logvar,
    float* __restrict__ partials,
    int C, int Z, int tubeBlocks, int klBlocks)
{
    const int lane = threadIdx.x & 63;
    const int wave = threadIdx.x >> 6;
    const int bid  = blockIdx.x;
    constexpr int B = 16384;
    constexpr int D = 512;

    float my = 0.0f;

    if (bid < tubeBlocks) {
        // gw in [0,4096); each wave owns 8 consecutive pairs (16 rows) of ONE
        // tensor (1024 waves per tensor — never crosses a boundary mid-wave).
        const int h   = lane >> 5;
        const int sub = lane & 31;
        const int gw  = bid * 4 + wave;
        const int p   = gw >> 10;
        const int idx0 = (gw & 1023) * 8;          // first pair within tensor
        const float* ab = (p == 0) ? xAr : (p == 1) ? xBr : (p == 2) ? xCr : comple_out;
        const float* lb = (p == 0) ? xA  : (p == 1) ? xB  : (p == 2) ? xC  : labels_enc;
        // byte address of this half-wave's first element: row (2*idx0+h), float4 sub
        const u64 aB = (u64)(const void*)ab + (u64)(2 * idx0 + h) * (D * 4) + (u64)sub * 16;
        const u64 lB = (u64)(const void*)lb + (u64)(2 * idx0 + h) * (D * 4) + (u64)sub * 16;

        f32x4 aA0, aA1, aA2, aA3, lA0, lA1, lA2, lA3;   // pipeline set A
        f32x4 aB0, aB1, aB2, aB3, lB0, lB1, lB2, lB3;   // pipeline set B
        float acc = 0.0f;

        // ---- 2-deep static pipeline over 8 pairs (pair i at byte +i*4096) ----
        TLOAD(aA0,aA1,aA2,aA3,lA0,lA1,lA2,lA3, aB + 0ull*4096, lB + 0ull*4096);
        TLOAD(aB0,aB1,aB2,aB3,lB0,lB1,lB2,lB3, aB + 1ull*4096, lB + 1ull*4096);
        VMWAIT8(); tubeCompute(aA0,aA1,aA2,aA3,lA0,lA1,lA2,lA3, acc);
        TLOAD(aA0,aA1,aA2,aA3,lA0,lA1,lA2,lA3, aB + 2ull*4096, lB + 2ull*4096);
        VMWAIT8(); tubeCompute(aB0,aB1,aB2,aB3,lB0,lB1,lB2,lB3, acc);
        TLOAD(aB0,aB1,aB2,aB3,lB0,lB1,lB2,lB3, aB + 3ull*4096, lB + 3ull*4096);
        VMWAIT8(); tubeCompute(aA0,aA1,aA2,aA3,lA0,lA1,lA2,lA3, acc);
        TLOAD(aA0,aA1,aA2,aA3,lA0,lA1,lA2,lA3, aB + 4ull*4096, lB + 4ull*4096);
        VMWAIT8(); tubeCompute(aB0,aB1,aB2,aB3,lB0,lB1,lB2,lB3, acc);
        TLOAD(aB0,aB1,aB2,aB3,lB0,lB1,lB2,lB3, aB + 5ull*4096, lB + 5ull*4096);
        VMWAIT8(); tubeCompute(aA0,aA1,aA2,aA3,lA0,lA1,lA2,lA3, acc);
        TLOAD(aA0,aA1,aA2,aA3,lA0,lA1,lA2,lA3, aB + 6ull*4096, lB + 6ull*4096);
        VMWAIT8(); tubeCompute(aB0,aB1,aB2,aB3,lB0,lB1,lB2,lB3, acc);
        TLOAD(aB0,aB1,aB2,aB3,lB0,lB1,lB2,lB3, aB + 7ull*4096, lB + 7ull*4096);
        VMWAIT8(); tubeCompute(aA0,aA1,aA2,aA3,lA0,lA1,lA2,lA3, acc);
        VMWAIT0(); tubeCompute(aB0,aB1,aB2,aB3,lB0,lB1,lB2,lB3, acc);

        my = acc * (1.0f / (32.0f * (float)B));
    } else if (bid < tubeBlocks + klBlocks) {
        // ---- KL: two coalesced float4 sweeps, one pair per thread each ----
        const int base = (bid - tubeBlocks) * 512 + threadIdx.x;
        const int i0 = base, i1 = base + 256;
        const f32x4* mu4 = (const f32x4*)mu;
        const f32x4* lv4 = (const f32x4*)logvar;
        f32x4 m0 = mu4[i0], l0 = lv4[i0], m1 = mu4[i1], l1 = lv4[i1];
        float acc = (1.0f + l0.x - m0.x * m0.x - __expf(l0.x))
                  + (1.0f + l0.y - m0.y * m0.y - __expf(l0.y))
                  + (1.0f + l0.z - m0.z * m0.z - __expf(l0.z))
                  + (1.0f + l0.w - m0.w * m0.w - __expf(l0.w))
                  + (1.0f + l1.x - m1.x * m1.x - __expf(l1.x))
                  + (1.0f + l1.y - m1.y * m1.y - __expf(l1.y))
                  + (1.0f + l1.z - m1.z * m1.z - __expf(l1.z))
                  + (1.0f + l1.w - m1.w * m1.w - __expf(l1.w));
        my = acc * (-0.5f * kBeta / ((float)B * (float)Z));
    } else {
        // ---- CE: one row per wave over C=100 ----
        const int r = (bid - tubeBlocks - klBlocks) * 4 + wave;   // < B
        const float* lrow = labels     + (size_t)r * C;
        const float* frow = fusion_out + (size_t)r * C;
        const bool has0 = (lane < C);
        const bool has1 = (lane + 64 < C);
        float v0 = has0 ? lrow[lane]      : -INFINITY;
        float v1 = has1 ? lrow[lane + 64] : -INFINITY;
        float f0 = has0 ? frow[lane]      : -INFINITY;
        float f1 = has1 ? frow[lane + 64] : -INFINITY;
        float bv; int bi;
        if (v1 > v0) { bv = v1; bi = lane + 64; } else { bv = v0; bi = lane; }
#pragma unroll
        for (int off = 32; off > 0; off >>= 1) {
            float ov = __shfl_xor(bv, off, 64);
            int   oi = __shfl_xor(bi, off, 64);
            if (ov > bv || (ov == bv && oi < bi)) { bv = ov; bi = oi; }
        }
        float m = fmaxf(f0, f1);
#pragma unroll
        for (int off = 32; off > 0; off >>= 1) m = fmaxf(m, __shfl_xor(m, off, 64));
        float e = 0.0f;
        if (has0) e += __expf(f0 - m);
        if (has1) e += __expf(f1 - m);
        e = waveSum(e);
        float tgt = (bi < 64) ? __shfl(f0, bi, 64) : __shfl(f1, bi - 64, 64);
        if (lane == 0) my = -(tgt - m - __logf(e)) / (float)B;
    }

    // ---- block reduce -> per-block partial (no atomics) ----
    float s = waveSum(my);
    __shared__ float sw[4];
    if (lane == 0) sw[wave] = s;
    __syncthreads();
    if (threadIdx.x == 0)
        partials[bid] = sw[0] + sw[1] + sw[2] + sw[3];
}

__global__ __launch_bounds__(256) void reduce_partials(
    const float* __restrict__ partials, float* __restrict__ out, int n)
{
    float s = 0.0f;
    for (int i = threadIdx.x; i < n; i += 256) s += partials[i];
    s = waveSum(s);
    __shared__ float sw[4];
    const int lane = threadIdx.x & 63;
    const int wave = threadIdx.x >> 6;
    if (lane == 0) sw[wave] = s;
    __syncthreads();
    if (threadIdx.x == 0) out[0] = sw[0] + sw[1] + sw[2] + sw[3];
}

extern "C" void kernel_launch(void* const* d_in, const int* in_sizes, int n_in,
                              void* d_out, int out_size, void* d_ws, size_t ws_size,
                              hipStream_t stream) {
    const float* fusion_out = (const float*)d_in[0];
    const float* comple_out = (const float*)d_in[1];
    const float* labels     = (const float*)d_in[2];
    const float* labels_enc = (const float*)d_in[3];
    const float* xA  = (const float*)d_in[4];
    const float* xAr = (const float*)d_in[5];
    const float* xB  = (const float*)d_in[6];
    const float* xBr = (const float*)d_in[7];
    const float* xC  = (const float*)d_in[8];
    const float* xCr = (const float*)d_in[9];
    const float* mu  = (const float*)d_in[10];
    const float* lv  = (const float*)d_in[11];
    float* out = (float*)d_out;
    float* ws  = (float*)d_ws;

    const int B = 16384;
    const int C = in_sizes[0] / B;    // 100
    const int Z = in_sizes[10] / B;   // 128

    const int tubeBlocks = 1024;                 // 4096 waves x 8 pairs = 32768 pairs
    const int klBlocks   = (B * Z / 4) / 512;    // 1024
    const int ceBlocks   = B / 4;                // 4096
    const int totalBlocks = tubeBlocks + klBlocks + ceBlocks;   // 6144

    fused_loss_partials<<<totalBlocks, 256, 0, stream>>>(
        fusion_out, comple_out, labels, labels_enc,
        xA, xAr, xB, xBr, xC, xCr, mu, lv,
        ws, C, Z, tubeBlocks, klBlocks);
    reduce_partials<<<1, 256, 0, stream>>>(ws, out, totalBlocks);
}

// Round 6
// 283.488 us; speedup vs baseline: 1.0382x; 1.0297x over previous
//
#include <hip/hip_runtime.h>
#include <math.h>

static constexpr float kL1   = 0.5f;
static constexpr float kL2   = 1.5f;
static constexpr float kBeta = 50000000.0f;
static constexpr float kEps  = 1e-08f;

typedef float f32x4 __attribute__((ext_vector_type(4)));

__device__ __forceinline__ float waveSum(float v) {
#pragma unroll
    for (int off = 32; off > 0; off >>= 1) v += __shfl_xor(v, off, 64);
    return v;
}

__device__ __forceinline__ float tubeTail(float dot, float pp, float gg) {
    float p_norm = sqrtf(pp);
    float g_norm = sqrtf(gg);
    float denom  = p_norm * g_norm;
    float cosine = (denom == 0.0f) ? 0.0f : dot / denom;
    float s_s    = 1.0f - cosine * cosine;
    float sine   = (s_s < 0.0f) ? 0.0f : sqrtf((s_s <= 0.0f) ? kEps : s_s);
    float gd     = (g_norm == 0.0f) ? (g_norm + kEps) : g_norm;
    float pc     = p_norm * cosine;
    float r_all  = pc / gd;
    float base   = p_norm * sine + fabsf(g_norm - pc);
    float ds     = (r_all >= 1.0f) ? (kL1 * base)
                 : ((r_all >= 0.0f) ? base
                                    : kL2 * fabsf(pc - g_norm - p_norm * sine));
    // -log(tanh(t)) = log(1+e^{-2t}) - log(1-e^{-2t})
    float t  = 1.0f / ds;
    float em = __expf(-2.0f * t);
    return __logf(1.0f + em) - __logf(fmaxf(1.0f - em, 1e-30f));
}

#define ACC3(A, L)                                        \
    dot += A.x*L.x + A.y*L.y + A.z*L.z + A.w*L.w;         \
    pp  += A.x*A.x + A.y*A.y + A.z*A.z + A.w*A.w;         \
    gg  += L.x*L.x + L.y*L.y + L.z*L.z + L.w*L.w;

// One work-unit per wave (best-measured skeleton, r2: 103.8us), plus a
// bijective XCD swizzle: hardware assigns block b to XCD b%8 (round-robin),
// so mapping work = (b%8)*chunk + b/8 gives each XCD one CONTIGUOUS work
// range -> each XCD streams a few large contiguous tensor slabs instead of
// 8-way interleaved 2KB stripes (T1 mechanism; the last untested lever for
// the served-BW pin at ~2.84 TB/s).
//   work [0, tubeBlocks)              : tube — 1 row-pair per wave
//   work [tubeBlocks, +klBlocks)      : KL   — 1 float4-pair per thread (exact)
//   work [tubeBlocks+klBlocks, end)   : CE   — 1 row per wave
__global__ __launch_bounds__(256) void fused_loss_partials(
    const float* __restrict__ fusion_out, const float* __restrict__ comple_out,
    const float* __restrict__ labels,     const float* __restrict__ labels_enc,
    const float* __restrict__ xA,  const float* __restrict__ xAr,
    const float* __restrict__ xB,  const float* __restrict__ xBr,
    const float* __restrict__ xC,  const float* __restrict__ xCr,
    const float* __restrict__ mu,  const float* __restrict__ logvar,
    float* __restrict__ partials,
    int C, int Z, int tubeBlocks, int klBlocks)
{
    const int lane = threadIdx.x & 63;
    const int wave = threadIdx.x >> 6;
    constexpr int B = 16384;
    constexpr int D = 512;

    // bijective XCD-contiguity swizzle (gridDim.x divisible by 8)
    const int chunk = gridDim.x >> 3;
    const int bid   = (blockIdx.x & 7) * chunk + (blockIdx.x >> 3);

    float my = 0.0f;

    if (bid < tubeBlocks) {
        // ---- TUBE: pair t = rows (2t, 2t+1); half-wave h owns row 2t+h ----
        const int t   = bid * 4 + wave;            // [0, 32768)
        const int h   = lane >> 5;
        const int sub = lane & 31;
        const int p   = t >> 13;                   // tensor index (8192 pairs each)
        const int r   = (2 * t) & (B - 1);         // first row of the pair
        const float* ab = (p == 0) ? xAr : (p == 1) ? xBr : (p == 2) ? xCr : comple_out;
        const float* lb = (p == 0) ? xA  : (p == 1) ? xB  : (p == 2) ? xC  : labels_enc;
        const f32x4* a = (const f32x4*)(ab + (size_t)r * D) + (h * 128 + sub);
        const f32x4* l = (const f32x4*)(lb + (size_t)r * D) + (h * 128 + sub);
        // 8 independent loads, consumed immediately — small live set
        f32x4 A0 = a[0], A1 = a[32], A2 = a[64], A3 = a[96];
        f32x4 L0 = l[0], L1 = l[32], L2 = l[64], L3 = l[96];
        float dot = 0.0f, pp = 0.0f, gg = 0.0f;
        ACC3(A0, L0); ACC3(A1, L1); ACC3(A2, L2); ACC3(A3, L3);
        // 5-step butterfly within each 32-lane half
#pragma unroll
        for (int off = 16; off > 0; off >>= 1) {
            dot += __shfl_xor(dot, off, 64);
            pp  += __shfl_xor(pp,  off, 64);
            gg  += __shfl_xor(gg,  off, 64);
        }
        // both rows' tails in parallel on the two halves (replicated x32 per half)
        my = tubeTail(dot, pp, gg) * (1.0f / (32.0f * (float)B));
    } else if (bid < tubeBlocks + klBlocks) {
        // ---- KL: exactly one float4 of mu + logvar per thread ----
        const int tid = (bid - tubeBlocks) * 256 + threadIdx.x;   // < B*Z/4 exactly
        const f32x4 m = ((const f32x4*)mu)[tid];
        const f32x4 l = ((const f32x4*)logvar)[tid];
        float acc = (1.0f + l.x - m.x * m.x - __expf(l.x))
                  + (1.0f + l.y - m.y * m.y - __expf(l.y))
                  + (1.0f + l.z - m.z * m.z - __expf(l.z))
                  + (1.0f + l.w - m.w * m.w - __expf(l.w));
        my = acc * (-0.5f * kBeta / ((float)B * (float)Z));
    } else {
        // ---- CE: one row per wave over C=100 ----
        const int r = (bid - tubeBlocks - klBlocks) * 4 + wave;   // < B
        const float* lrow = labels     + (size_t)r * C;
        const float* frow = fusion_out + (size_t)r * C;
        const bool has0 = (lane < C);
        const bool has1 = (lane + 64 < C);
        float v0 = has0 ? lrow[lane]      : -INFINITY;
        float v1 = has1 ? lrow[lane + 64] : -INFINITY;
        float f0 = has0 ? frow[lane]      : -INFINITY;
        float f1 = has1 ? frow[lane + 64] : -INFINITY;
        float bv; int bi;
        if (v1 > v0) { bv = v1; bi = lane + 64; } else { bv = v0; bi = lane; }
#pragma unroll
        for (int off = 32; off > 0; off >>= 1) {
            float ov = __shfl_xor(bv, off, 64);
            int   oi = __shfl_xor(bi, off, 64);
            if (ov > bv || (ov == bv && oi < bi)) { bv = ov; bi = oi; }
        }
        float m = fmaxf(f0, f1);
#pragma unroll
        for (int off = 32; off > 0; off >>= 1) m = fmaxf(m, __shfl_xor(m, off, 64));
        float e = 0.0f;
        if (has0) e += __expf(f0 - m);
        if (has1) e += __expf(f1 - m);
        e = waveSum(e);
        float tgt = (bi < 64) ? __shfl(f0, bi, 64) : __shfl(f1, bi - 64, 64);
        if (lane == 0) my = -(tgt - m - __logf(e)) / (float)B;
    }

    // ---- block reduce -> per-work-id partial (bijection: sum unaffected) ----
    float s = waveSum(my);
    __shared__ float sw[4];
    if (lane == 0) sw[wave] = s;
    __syncthreads();
    if (threadIdx.x == 0)
        partials[bid] = sw[0] + sw[1] + sw[2] + sw[3];
}

__global__ __launch_bounds__(256) void reduce_partials(
    const float* __restrict__ partials, float* __restrict__ out, int n4)
{
    // n4 = number of float4 chunks (grid guaranteed divisible by 4)
    const f32x4* p4 = (const f32x4*)partials;
    float s = 0.0f;
    for (int i = threadIdx.x; i < n4; i += 256) {
        f32x4 v = p4[i];
        s += v.x + v.y + v.z + v.w;
    }
    s = waveSum(s);
    __shared__ float sw[4];
    const int lane = threadIdx.x & 63;
    const int wave = threadIdx.x >> 6;
    if (lane == 0) sw[wave] = s;
    __syncthreads();
    if (threadIdx.x == 0) out[0] = sw[0] + sw[1] + sw[2] + sw[3];
}

extern "C" void kernel_launch(void* const* d_in, const int* in_sizes, int n_in,
                              void* d_out, int out_size, void* d_ws, size_t ws_size,
                              hipStream_t stream) {
    const float* fusion_out = (const float*)d_in[0];
    const float* comple_out = (const float*)d_in[1];
    const float* labels     = (const float*)d_in[2];
    const float* labels_enc = (const float*)d_in[3];
    const float* xA  = (const float*)d_in[4];
    const float* xAr = (const float*)d_in[5];
    const float* xB  = (const float*)d_in[6];
    const float* xBr = (const float*)d_in[7];
    const float* xC  = (const float*)d_in[8];
    const float* xCr = (const float*)d_in[9];
    const float* mu  = (const float*)d_in[10];
    const float* lv  = (const float*)d_in[11];
    float* out = (float*)d_out;
    float* ws  = (float*)d_ws;

    const int B = 16384;
    const int C = in_sizes[0] / B;    // 100
    const int Z = in_sizes[10] / B;   // 128

    const int tubeBlocks = (4 * B / 2) / 4;      // 8192: 1 pair/wave, 4 waves/block
    const int klBlocks   = (B * Z / 4) / 256;    // 2048: 1 float4-pair/thread
    const int ceBlocks   = B / 4;                // 4096: 1 row/wave
    const int totalBlocks = tubeBlocks + klBlocks + ceBlocks;   // 14336 (%8==0, %4==0)

    fused_loss_partials<<<totalBlocks, 256, 0, stream>>>(
        fusion_out, comple_out, labels, labels_enc,
        xA, xAr, xB, xBr, xC, xCr, mu, lv,
        ws, C, Z, tubeBlocks, klBlocks);
    reduce_partials<<<1, 256, 0, stream>>>(ws, out, totalBlocks / 4);
}